// Round 4
// baseline (225.871 us; speedup 1.0000x reference)
//
#include <hip/hip_runtime.h>
#include <math.h>

#define B_ 8
#define C_ 256
#define N_ 4096          // H*W
#define NPOS 32768       // B*N
#define SCALE_ 0.1767766952966369f
#define EPS_ 1e-5f

typedef __attribute__((ext_vector_type(8))) short bf16x8;
typedef __attribute__((ext_vector_type(8))) unsigned short u16x8;
typedef __attribute__((ext_vector_type(4))) float f32x4;

__device__ __forceinline__ unsigned short f2bf(float f) {
  union { float f; unsigned u; } v; v.f = f;
  unsigned r = v.u + 0x7fff + ((v.u >> 16) & 1);   // RNE
  return (unsigned short)(r >> 16);
}
__device__ __forceinline__ float bf2f(unsigned short u) {
  union { unsigned u; float f; } v; v.u = ((unsigned)u) << 16; return v.f;
}
__device__ __forceinline__ float blo(unsigned u) {
  union { unsigned u; float f; } v; v.u = u << 16; return v.f;
}
__device__ __forceinline__ float bhi(unsigned u) {
  union { unsigned u; float f; } v; v.u = u & 0xffff0000u; return v.f;
}

#define GLD_LDS16(g, l) \
  __builtin_amdgcn_global_load_lds((const __attribute__((address_space(1))) unsigned int*)(g), \
                                   (__attribute__((address_space(3))) unsigned int*)(l), 16, 0, 0)

// ---- kernel 1: fused stream + transpose + weight prep ----
// blk 0..2     : G[o]=sum_c bf16(W[o,c]*g[c]), Bb[o]=sum_c W[o,c]*beta[c]  (768 rows)
// blk 3..258   : weight cvt; wqb = bf16(W_qkv * gamma) (gamma folded), pwb = bf16(proj_w)
// blk 259..1282: stream (b, 32-ch chunk, 256-pos group):
//   write subB/viB bf16 BCHW, xpos bf16 [NPOS,256] slice (LDS transpose),
//   partials[chunk][p] = {sum, sumsq}. One barrier.
__global__ __launch_bounds__(256, 4) void k_stream(
    const float* __restrict__ vi, const float* __restrict__ ir,
    const float* __restrict__ wq, const float* __restrict__ pw,
    const float* __restrict__ ln_g, const float* __restrict__ ln_b,
    unsigned short* __restrict__ wdst,
    unsigned short* __restrict__ subB, unsigned short* __restrict__ viB,
    unsigned short* __restrict__ xpos,
    float2* __restrict__ partials, float* __restrict__ Gv, float* __restrict__ Bbv)
{
  int t = threadIdx.x;
  int blk = blockIdx.x;
  if (blk < 3) {                       // G/Bb rows (scheduled first: long serial loop)
    int o = blk * 256 + t;             // 0..767
    float g = 0.f, bb = 0.f;
    #pragma unroll 8
    for (int c = 0; c < 256; ++c) {
      float w = wq[o * 256 + c];
      g += bf2f(f2bf(w * ln_g[c]));    // match MFMA's rounded weights exactly
      bb += w * ln_b[c];
    }
    Gv[o] = g; Bbv[o] = bb;
    return;
  }
  if (blk < 259) {                     // weight cvt (gamma-fused for wq)
    int i4 = (blk - 3) * 256 + t;      // 65536 float4s
    ushort4 o;
    if (i4 < 49152) {
      float4 v = ((const float4*)wq)[i4];
      int c = (i4 << 2) & 255;
      v.x *= ln_g[c]; v.y *= ln_g[c + 1]; v.z *= ln_g[c + 2]; v.w *= ln_g[c + 3];
      o.x = f2bf(v.x); o.y = f2bf(v.y); o.z = f2bf(v.z); o.w = f2bf(v.w);
    } else {
      float4 v = ((const float4*)pw)[i4 - 49152];
      o.x = f2bf(v.x); o.y = f2bf(v.y); o.z = f2bf(v.z); o.w = f2bf(v.w);
    }
    ((ushort4*)wdst)[i4] = o;
    return;
  }
  __shared__ float redS[4 * 256], redQ[4 * 256];
  __shared__ __align__(16) unsigned short tile2[32 * 264];  // [ch-in-chunk][pos], pad 8
  int sblk = blk - 259;        // b*128 + chunk*16 + pgrp
  int b = sblk >> 7;
  int chunk = (sblk >> 4) & 7;
  int pgrp = sblk & 15;
  int posq = t & 63;           // 64 position-quads (= lane)
  int cg = t >> 6;             // wave id = channel subgroup (8 ch each)
  int c0 = chunk * 32 + cg * 8;
  int n0 = pgrp * 256 + posq * 4;
  size_t base = ((size_t)b * C_ + c0) * N_ + n0;

  // issue all 16 loads first (MLP), then compute + stores
  float4 V[8], I[8];
  #pragma unroll
  for (int j = 0; j < 8; ++j) V[j] = *(const float4*)&vi[base + (size_t)j * N_];
  #pragma unroll
  for (int j = 0; j < 8; ++j) I[j] = *(const float4*)&ir[base + (size_t)j * N_];

  float s0 = 0.f, s1 = 0.f, s2 = 0.f, s3 = 0.f;
  float q0 = 0.f, q1 = 0.f, q2 = 0.f, q3 = 0.f;
  #pragma unroll
  for (int j = 0; j < 8; ++j) {
    float4 v4 = V[j], i4 = I[j];
    float4 sv;
    sv.x = v4.x - i4.x; sv.y = v4.y - i4.y; sv.z = v4.z - i4.z; sv.w = v4.w - i4.w;
    ushort4 sb, vb;
    sb.x = f2bf(sv.x); sb.y = f2bf(sv.y); sb.z = f2bf(sv.z); sb.w = f2bf(sv.w);
    vb.x = f2bf(v4.x); vb.y = f2bf(v4.y); vb.z = f2bf(v4.z); vb.w = f2bf(v4.w);
    *(ushort4*)&subB[base + (size_t)j * N_] = sb;
    *(ushort4*)&viB[base + (size_t)j * N_] = vb;
    // LDS transpose tile: contiguous 8B/lane -> conflict-free ds_write_b64
    *(ushort4*)&tile2[(cg * 8 + j) * 264 + posq * 4] = sb;
    s0 += sv.x; q0 += sv.x * sv.x;
    s1 += sv.y; q1 += sv.y * sv.y;
    s2 += sv.z; q2 += sv.z * sv.z;
    s3 += sv.w; q3 += sv.w * sv.w;
  }
  // per-wave partial (8 channels) for 4 positions -> LDS
  *(f32x4*)&redS[cg * 256 + posq * 4] = (f32x4){s0, s1, s2, s3};
  *(f32x4*)&redQ[cg * 256 + posq * 4] = (f32x4){q0, q1, q2, q3};
  __syncthreads();
  // thread t owns block-position t: partials + transposed xpos row slice
  {
    float s = redS[t] + redS[256 + t] + redS[512 + t] + redS[768 + t];
    float q = redQ[t] + redQ[256 + t] + redQ[512 + t] + redQ[768 + t];
    partials[(size_t)chunk * NPOS + b * 4096 + pgrp * 256 + t] = make_float2(s, q);
  }
  {
    u16x8 o0, o1, o2, o3;
    #pragma unroll
    for (int wc = 0; wc < 8; ++wc) {
      o0[wc] = tile2[wc * 264 + t];
      o1[wc] = tile2[(wc + 8) * 264 + t];
      o2[wc] = tile2[(wc + 16) * 264 + t];
      o3[wc] = tile2[(wc + 24) * 264 + t];
    }
    size_t xr = ((size_t)b * 4096 + pgrp * 256 + t) * 256 + chunk * 32;
    *(u16x8*)&xpos[xr] = o0;
    *(u16x8*)&xpos[xr + 8] = o1;
    *(u16x8*)&xpos[xr + 16] = o2;
    *(u16x8*)&xpos[xr + 24] = o3;
  }
}

// ---------------- MFMA GEMM: C[M,N] = A[M,256] * B[N,256]^T ----------------
// EPI=2: A = raw sub [NPOS,256]; LN folded into epilogue:
//   out = rstd_m*acc + (-mu_m*rstd_m)*G[o] + Bb[o]   (B = W*gamma, bf16)
// EPI=1: proj GEMM, residual-add epilogue into BCHW.
template<int EPI, int NT>
__global__ __launch_bounds__(256) void k_gemm_mfma(
    const unsigned short* __restrict__ A,
    const unsigned short* __restrict__ Bw,
    unsigned short* __restrict__ Cout,
    const float* __restrict__ bias,
    const unsigned short* __restrict__ subB,
    int ldc,
    const float2* __restrict__ partials,
    const float* __restrict__ Gv,
    const float* __restrict__ Bbv)
{
  __shared__ __align__(16) unsigned short As[128 * 32];
  __shared__ __align__(16) unsigned short Bs[128 * 32];
  __shared__ __align__(16) unsigned short Cs[64 * 136];
  __shared__ float aS[128], bS[128], Gs[128], Bb2[128];
  int flat = blockIdx.x;
  int xcd = flat & 7;
  int l = flat >> 3;
  int ml = l / NT;
  int nn = l - ml * NT;
  int m0 = (xcd * 32 + ml) * 128;
  int n0 = nn * 128;
  int tid = threadIdx.x;
  int wv = tid >> 6;
  int lane = tid & 63;
  int mw = (wv >> 1) * 64, nw = (wv & 1) * 64;
  int r = lane & 15, q = lane >> 4;

  if (EPI == 2) {
    if (tid < 128) {
      int p = m0 + tid;
      float s = 0.f, qq = 0.f;
      #pragma unroll
      for (int ch = 0; ch < 8; ++ch) {
        float2 pp = partials[(size_t)ch * NPOS + p];
        s += pp.x; qq += pp.y;
      }
      float mu = s * (1.f / 256.f);
      float var = qq * (1.f / 256.f) - mu * mu;
      float rs = rsqrtf(var + EPS_);
      aS[tid] = rs;
      bS[tid] = -mu * rs;
      Gs[tid] = Gv[n0 + tid];
      Bb2[tid] = Bbv[n0 + tid];
    }
  }

  int seg0 = wv * 2;
  int srow0 = seg0 * 16 + (lane >> 2);
  int scol = (lane & 3) * 8;
  const unsigned short* ga0 = A  + (size_t)(m0 + srow0) * 256 + scol;
  const unsigned short* ga1 = ga0 + 16 * 256;
  const unsigned short* gb0 = Bw + (size_t)(n0 + srow0) * 256 + scol;
  const unsigned short* gb1 = gb0 + 16 * 256;
  unsigned short* la0 = &As[seg0 * 512];
  unsigned short* la1 = la0 + 512;
  unsigned short* lb0 = &Bs[seg0 * 512];
  unsigned short* lb1 = lb0 + 512;

  f32x4 acc[4][4];
  #pragma unroll
  for (int i = 0; i < 4; ++i)
    #pragma unroll
    for (int j = 0; j < 4; ++j)
      acc[i][j] = (f32x4){0.f, 0.f, 0.f, 0.f};

  for (int k0 = 0; k0 < 256; k0 += 32) {
    GLD_LDS16(ga0 + k0, la0);
    GLD_LDS16(ga1 + k0, la1);
    GLD_LDS16(gb0 + k0, lb0);
    GLD_LDS16(gb1 + k0, lb1);
    __syncthreads();
    bf16x8 af[4], bfr[4];
    #pragma unroll
    for (int mt = 0; mt < 4; ++mt)
      af[mt] = *(const bf16x8*)&As[(mw + mt * 16 + r) * 32 + q * 8];
    #pragma unroll
    for (int nt = 0; nt < 4; ++nt)
      bfr[nt] = *(const bf16x8*)&Bs[(nw + nt * 16 + r) * 32 + q * 8];
    #pragma unroll
    for (int mt = 0; mt < 4; ++mt)
      #pragma unroll
      for (int nt = 0; nt < 4; ++nt)
        acc[mt][nt] = __builtin_amdgcn_mfma_f32_16x16x32_bf16(af[mt], bfr[nt], acc[mt][nt], 0, 0, 0);
    __syncthreads();
  }

  int b = m0 >> 12;
  int nn0 = m0 & 4095;
  #pragma unroll
  for (int pass = 0; pass < 2; ++pass) {
    __syncthreads();
    if (EPI != 1) {
      if ((wv >> 1) == pass) {
        #pragma unroll
        for (int mt = 0; mt < 4; ++mt) {
          int lr = mt * 16 + q * 4;
          #pragma unroll
          for (int nt = 0; nt < 4; ++nt) {
            int col = nw + nt * 16 + r;
            #pragma unroll
            for (int rr = 0; rr < 4; ++rr) {
              float vv = acc[mt][nt][rr];
              if (EPI == 2) {
                int mrow = pass * 64 + lr + rr;
                vv = fmaf(vv, aS[mrow], fmaf(bS[mrow], Gs[col], Bb2[col]));
              }
              Cs[(lr + rr) * 136 + col] = f2bf(vv);
            }
          }
        }
      }
    } else {
      if ((wv & 1) == pass) {
        #pragma unroll
        for (int nt = 0; nt < 4; ++nt) {
          int lr = nt * 16 + r;
          #pragma unroll
          for (int mt = 0; mt < 4; ++mt) {
            int pc = mw + mt * 16 + q * 4;
            #pragma unroll
            for (int rr = 0; rr < 4; ++rr)
              Cs[lr * 136 + pc + rr] = f2bf(acc[mt][nt][rr]);
          }
        }
      }
    }
    __syncthreads();
    if (EPI != 1) {
      #pragma unroll
      for (int cc = 0; cc < 4; ++cc) {
        int ch = cc * 256 + tid;
        int row = ch >> 4, cg = ch & 15;
        u16x8 cv = *(const u16x8*)&Cs[row * 136 + cg * 8];
        int m = m0 + pass * 64 + row;
        *(u16x8*)&Cout[(size_t)m * ldc + n0 + cg * 8] = cv;
      }
    } else {
      #pragma unroll
      for (int cc = 0; cc < 4; ++cc) {
        int ch = cc * 256 + tid;
        int row = ch >> 4, cg = ch & 15;
        u16x8 cv = *(const u16x8*)&Cs[row * 136 + cg * 8];
        int c = n0 + pass * 64 + row;
        size_t idx = ((size_t)(b * 256 + c)) * 4096 + nn0 + cg * 8;
        u16x8 sv = *(const u16x8*)&subB[idx];
        float bb = bias[c];
        u16x8 ov;
        #pragma unroll
        for (int e = 0; e < 8; ++e)
          ov[e] = f2bf(bf2f((unsigned short)cv[e]) + bb + bf2f((unsigned short)sv[e]));
        *(u16x8*)&Cout[idx] = ov;
      }
    }
  }
}

// ---------------- kernel 3: dilated local attention ----------------
__global__ __launch_bounds__(256) void k_attn(
    const unsigned short* __restrict__ qkv,   // [NPOS, 768] bf16
    unsigned short* __restrict__ y)           // [NPOS, 256] bf16
{
  int t = threadIdx.x;
  int sub = t >> 2;
  int lane4 = t & 3;
  int item = blockIdx.x * 64 + sub;
  int ih = item & 7;
  int p = item >> 3;
  int i = ih >> 1, h = ih & 1;
  int dil = i + 1;
  int b = p >> 12;
  int n = p & 4095;
  int py = n >> 6, px = n & 63;
  int off = i * 64 + h * 32 + lane4 * 8;
  const unsigned short* base = qkv + off;

  uint4 qw = *(const uint4*)(base + (size_t)p * 768);
  float q0 = blo(qw.x), q1 = bhi(qw.x), q2 = blo(qw.y), q3 = bhi(qw.y),
        q4 = blo(qw.z), q5 = bhi(qw.z), q6 = blo(qw.w), q7 = bhi(qw.w);

  int pj[9];
  #pragma unroll
  for (int j = 0; j < 9; ++j) {
    int ny = py + (j / 3 - 1) * dil;
    int nx = px + (j % 3 - 1) * dil;
    bool ok = ((unsigned)ny < 64u) && ((unsigned)nx < 64u);
    pj[j] = ok ? ((b << 12) + (ny << 6) + nx) : -1;
  }

  float sc[9];
  #pragma unroll
  for (int j = 0; j < 9; ++j) {
    float s = 0.f;
    if (pj[j] >= 0) {
      uint4 kw = *(const uint4*)(base + 256 + (size_t)pj[j] * 768);
      s  = q0 * blo(kw.x) + q1 * bhi(kw.x);
      s += q2 * blo(kw.y) + q3 * bhi(kw.y);
      s += q4 * blo(kw.z) + q5 * bhi(kw.z);
      s += q6 * blo(kw.w) + q7 * bhi(kw.w);
    }
    s += __shfl_xor(s, 1, 4);
    s += __shfl_xor(s, 2, 4);
    sc[j] = s * SCALE_;             // zero-pad taps -> score exactly 0
  }

  float mx = sc[0];
  #pragma unroll
  for (int j = 1; j < 9; ++j) mx = fmaxf(mx, sc[j]);
  float e[9], ssum = 0.f;
  #pragma unroll
  for (int j = 0; j < 9; ++j) { e[j] = __expf(sc[j] - mx); ssum += e[j]; }
  float inv = 1.f / ssum;

  float o0 = 0.f, o1 = 0.f, o2 = 0.f, o3 = 0.f, o4 = 0.f, o5 = 0.f, o6 = 0.f, o7 = 0.f;
  #pragma unroll
  for (int j = 0; j < 9; ++j) {
    if (pj[j] >= 0) {
      float w = e[j] * inv;
      uint4 vw = *(const uint4*)(base + 512 + (size_t)pj[j] * 768);
      o0 += w * blo(vw.x); o1 += w * bhi(vw.x);
      o2 += w * blo(vw.y); o3 += w * bhi(vw.y);
      o4 += w * blo(vw.z); o5 += w * bhi(vw.z);
      o6 += w * blo(vw.w); o7 += w * bhi(vw.w);
    }
  }

  u16x8 ov;
  ov[0] = f2bf(o0); ov[1] = f2bf(o1); ov[2] = f2bf(o2); ov[3] = f2bf(o3);
  ov[4] = f2bf(o4); ov[5] = f2bf(o5); ov[6] = f2bf(o6); ov[7] = f2bf(o7);
  *(u16x8*)(y + (size_t)p * 256 + off) = ov;
}

// ---------------- kernel 5: per-(b,c) 64x64x64 MFMA matmul, dup output ----
__global__ __launch_bounds__(256) void k_bmm(
    const unsigned short* __restrict__ viB,
    const unsigned short* __restrict__ divmB,
    float* __restrict__ out)
{
  __shared__ __align__(16) unsigned short Vs[64 * 72];
  __shared__ __align__(16) unsigned short Ds[64 * 72];
  int bc = blockIdx.x;
  size_t base = (size_t)bc * 4096;
  int t = threadIdx.x;
  {
    int flat = t * 16;
    int row = flat >> 6, col = flat & 63;   // row: i for vi / k for div
    u16x8 v0 = *(const u16x8*)&viB[base + flat];
    u16x8 v1 = *(const u16x8*)&viB[base + flat + 8];
    *(u16x8*)&Vs[row * 72 + col] = v0;
    *(u16x8*)&Vs[row * 72 + col + 8] = v1;
    u16x8 d0 = *(const u16x8*)&divmB[base + flat];
    u16x8 d1 = *(const u16x8*)&divmB[base + flat + 8];
    #pragma unroll
    for (int e = 0; e < 8; ++e) {
      Ds[(col + e) * 72 + row] = (unsigned short)d0[e];       // Ds[j][k]
      Ds[(col + 8 + e) * 72 + row] = (unsigned short)d1[e];
    }
  }
  __syncthreads();
  int w = t >> 6, lane = t & 63;
  int r = lane & 15, q = lane >> 4;
  int wi = (w >> 1) * 32, wj = (w & 1) * 32;
  f32x4 acc[2][2];
  #pragma unroll
  for (int i = 0; i < 2; ++i)
    #pragma unroll
    for (int j = 0; j < 2; ++j)
      acc[i][j] = (f32x4){0.f, 0.f, 0.f, 0.f};
  #pragma unroll
  for (int ks = 0; ks < 2; ++ks) {
    bf16x8 a[2], bfr[2];
    #pragma unroll
    for (int ti = 0; ti < 2; ++ti)
      a[ti] = *(const bf16x8*)&Vs[(wi + ti * 16 + r) * 72 + ks * 32 + q * 8];
    #pragma unroll
    for (int tj = 0; tj < 2; ++tj)
      bfr[tj] = *(const bf16x8*)&Ds[(wj + tj * 16 + r) * 72 + ks * 32 + q * 8];
    #pragma unroll
    for (int ti = 0; ti < 2; ++ti)
      #pragma unroll
      for (int tj = 0; tj < 2; ++tj)
        acc[ti][tj] = __builtin_amdgcn_mfma_f32_16x16x32_bf16(a[ti], bfr[tj], acc[ti][tj], 0, 0, 0);
  }
  #pragma unroll
  for (int ti = 0; ti < 2; ++ti)
    #pragma unroll
    for (int tj = 0; tj < 2; ++tj)
      #pragma unroll
      for (int rr = 0; rr < 4; ++rr) {
        int row = wi + ti * 16 + q * 4 + rr;
        int col = wj + tj * 16 + r;
        float v = acc[ti][tj][rr];
        out[base + row * 64 + col] = v;
        out[8388608ull + base + row * 64 + col] = v;
      }
}

extern "C" void kernel_launch(void* const* d_in, const int* in_sizes, int n_in,
                              void* d_out, int out_size, void* d_ws, size_t ws_size,
                              hipStream_t stream) {
  const float* vi     = (const float*)d_in[0];
  const float* ir     = (const float*)d_in[1];
  const float* w_qkv  = (const float*)d_in[2];
  const float* proj_w = (const float*)d_in[3];
  const float* proj_b = (const float*)d_in[4];
  const float* ln_g   = (const float*)d_in[5];
  const float* ln_b   = (const float*)d_in[6];
  float* out = (float*)d_out;
  char* ws = (char*)d_ws;
  unsigned short* subB = (unsigned short*)(ws);                // 16.8 MB BCHW bf16
  unsigned short* qkvb = (unsigned short*)(ws + 16777216);     // 50.3 MB [NPOS,768]
  unsigned short* divmB= (unsigned short*)(ws + 16777216);     // reuse after attn
  unsigned short* xpos = (unsigned short*)(ws + 67108864);     // 16.8 MB sub [NPOS,256]
  unsigned short* yb   = (unsigned short*)(ws + 83886080);     // 16.8 MB [NPOS,256]
  unsigned short* viB  = (unsigned short*)(ws + 100663296);    // 16.8 MB BCHW bf16
  unsigned short* wqb  = (unsigned short*)(ws + 117440512);    // [768,256] bf16 (W*gamma)
  unsigned short* pwb  = wqb + 196608;                         // [256,256] bf16
  float2* partials     = (float2*)(ws + 125829120);            // 2 MB [8][NPOS]
  float* Gv            = (float*)(ws + 127926272);             // [768] f32
  float* Bbv           = (float*)(ws + 127930368);             // [768] f32

  k_stream<<<1283, 256, 0, stream>>>(vi, ir, w_qkv, proj_w, ln_g, ln_b,
                                     wqb, subB, viB, xpos, partials, Gv, Bbv);
  k_gemm_mfma<2, 6><<<1536, 256, 0, stream>>>(xpos, wqb, qkvb, nullptr, nullptr, 768,
                                              partials, Gv, Bbv);
  k_attn<<<4096, 256, 0, stream>>>(qkvb, yb);
  k_gemm_mfma<1, 2><<<512, 256, 0, stream>>>(yb, pwb, divmB, proj_b, subB, 0,
                                             nullptr, nullptr, nullptr);
  k_bmm<<<2048, 256, 0, stream>>>(viB, divmB, out);
}

// Round 5
// 215.997 us; speedup vs baseline: 1.0457x; 1.0457x over previous
//
#include <hip/hip_runtime.h>
#include <math.h>

#define B_ 8
#define C_ 256
#define N_ 4096          // H*W
#define NPOS 32768       // B*N
#define SCALE_ 0.1767766952966369f
#define EPS_ 1e-5f

typedef __attribute__((ext_vector_type(8))) short bf16x8;
typedef __attribute__((ext_vector_type(8))) unsigned short u16x8;
typedef __attribute__((ext_vector_type(4))) float f32x4;

__device__ __forceinline__ unsigned short f2bf(float f) {
  union { float f; unsigned u; } v; v.f = f;
  unsigned r = v.u + 0x7fff + ((v.u >> 16) & 1);   // RNE
  return (unsigned short)(r >> 16);
}
__device__ __forceinline__ float bf2f(unsigned short u) {
  union { unsigned u; float f; } v; v.u = ((unsigned)u) << 16; return v.f;
}
__device__ __forceinline__ float blo(unsigned u) {
  union { unsigned u; float f; } v; v.u = u << 16; return v.f;
}
__device__ __forceinline__ float bhi(unsigned u) {
  union { unsigned u; float f; } v; v.u = u & 0xffff0000u; return v.f;
}

#define GLD_LDS16(g, l) \
  __builtin_amdgcn_global_load_lds((const __attribute__((address_space(1))) unsigned int*)(g), \
                                   (__attribute__((address_space(3))) unsigned int*)(l), 16, 0, 0)

// ---- kernel 1: fused stream + transpose + weight prep ----
// blk 0..1023   : stream (b, 32-ch chunk, 256-pos group):
//   write subB/viB bf16 BCHW, xpos bf16 [NPOS,256] slice (LDS transpose),
//   partials[chunk][p] = {sum, sumsq}. One barrier.
// blk 1024..1279: weight cvt; wqb = bf16(W_qkv*gamma), pwb = bf16(proj_w).
//   qkv rows additionally wave-reduce G[o]=sum_c bf16(W*g), Bb[o]=sum_c W*beta
//   (one row per wave, 6-step shfl_xor -> lane0 store; replaces v5's serial
//   3-block gather chain that was a ~43us latency tail).
// launch_bounds(256,6): 1280 blocks all co-resident (LDS 25088*6 <= 160K).
__global__ __launch_bounds__(256, 6) void k_stream(
    const float* __restrict__ vi, const float* __restrict__ ir,
    const float* __restrict__ wq, const float* __restrict__ pw,
    const float* __restrict__ ln_g, const float* __restrict__ ln_b,
    unsigned short* __restrict__ wdst,
    unsigned short* __restrict__ subB, unsigned short* __restrict__ viB,
    unsigned short* __restrict__ xpos,
    float2* __restrict__ partials, float* __restrict__ Gv, float* __restrict__ Bbv)
{
  int t = threadIdx.x;
  int blk = blockIdx.x;
  if (blk >= 1024) {                   // weight cvt (+ G/Bb wave-reduce)
    int i4 = (blk - 1024) * 256 + t;   // 65536 float4s
    if (i4 < 49152) {
      float4 v = ((const float4*)wq)[i4];
      int c = (t & 63) * 4;
      float4 gq = *(const float4*)&ln_g[c];
      float4 bq = *(const float4*)&ln_b[c];
      ushort4 o;
      o.x = f2bf(v.x * gq.x); o.y = f2bf(v.y * gq.y);
      o.z = f2bf(v.z * gq.z); o.w = f2bf(v.w * gq.w);
      ((ushort4*)wdst)[i4] = o;
      float gp = bf2f(o.x) + bf2f(o.y) + bf2f(o.z) + bf2f(o.w);
      float bp = v.x * bq.x + v.y * bq.y + v.z * bq.z + v.w * bq.w;
      #pragma unroll
      for (int m = 1; m <= 32; m <<= 1) {
        gp += __shfl_xor(gp, m);
        bp += __shfl_xor(bp, m);
      }
      if ((t & 63) == 0) {
        int orow = i4 >> 6;            // one row per wave
        Gv[orow] = gp;
        Bbv[orow] = bp;
      }
    } else {
      float4 v = ((const float4*)pw)[i4 - 49152];
      ushort4 o;
      o.x = f2bf(v.x); o.y = f2bf(v.y); o.z = f2bf(v.z); o.w = f2bf(v.w);
      ((ushort4*)wdst)[i4] = o;
    }
    return;
  }
  __shared__ float redS[4 * 256], redQ[4 * 256];
  __shared__ __align__(16) unsigned short tile2[32 * 264];  // [ch-in-chunk][pos], pad 8
  int sblk = blk;              // b*128 + chunk*16 + pgrp
  int b = sblk >> 7;
  int chunk = (sblk >> 4) & 7;
  int pgrp = sblk & 15;
  int posq = t & 63;           // 64 position-quads (= lane)
  int cg = t >> 6;             // wave id = channel subgroup (8 ch each)
  int c0 = chunk * 32 + cg * 8;
  int n0 = pgrp * 256 + posq * 4;
  size_t base = ((size_t)b * C_ + c0) * N_ + n0;

  // issue all 16 loads first (MLP), then compute + stores
  float4 V[8], I[8];
  #pragma unroll
  for (int j = 0; j < 8; ++j) V[j] = *(const float4*)&vi[base + (size_t)j * N_];
  #pragma unroll
  for (int j = 0; j < 8; ++j) I[j] = *(const float4*)&ir[base + (size_t)j * N_];

  float s0 = 0.f, s1 = 0.f, s2 = 0.f, s3 = 0.f;
  float q0 = 0.f, q1 = 0.f, q2 = 0.f, q3 = 0.f;
  #pragma unroll
  for (int j = 0; j < 8; ++j) {
    float4 v4 = V[j], i4 = I[j];
    float4 sv;
    sv.x = v4.x - i4.x; sv.y = v4.y - i4.y; sv.z = v4.z - i4.z; sv.w = v4.w - i4.w;
    ushort4 sb, vb;
    sb.x = f2bf(sv.x); sb.y = f2bf(sv.y); sb.z = f2bf(sv.z); sb.w = f2bf(sv.w);
    vb.x = f2bf(v4.x); vb.y = f2bf(v4.y); vb.z = f2bf(v4.z); vb.w = f2bf(v4.w);
    *(ushort4*)&subB[base + (size_t)j * N_] = sb;
    *(ushort4*)&viB[base + (size_t)j * N_] = vb;
    // LDS transpose tile: contiguous 8B/lane -> conflict-free ds_write_b64
    *(ushort4*)&tile2[(cg * 8 + j) * 264 + posq * 4] = sb;
    s0 += sv.x; q0 += sv.x * sv.x;
    s1 += sv.y; q1 += sv.y * sv.y;
    s2 += sv.z; q2 += sv.z * sv.z;
    s3 += sv.w; q3 += sv.w * sv.w;
  }
  // per-wave partial (8 channels) for 4 positions -> LDS
  *(f32x4*)&redS[cg * 256 + posq * 4] = (f32x4){s0, s1, s2, s3};
  *(f32x4*)&redQ[cg * 256 + posq * 4] = (f32x4){q0, q1, q2, q3};
  __syncthreads();
  // thread t owns block-position t: partials + transposed xpos row slice
  {
    float s = redS[t] + redS[256 + t] + redS[512 + t] + redS[768 + t];
    float q = redQ[t] + redQ[256 + t] + redQ[512 + t] + redQ[768 + t];
    partials[(size_t)chunk * NPOS + b * 4096 + pgrp * 256 + t] = make_float2(s, q);
  }
  {
    u16x8 o0, o1, o2, o3;
    #pragma unroll
    for (int wc = 0; wc < 8; ++wc) {
      o0[wc] = tile2[wc * 264 + t];
      o1[wc] = tile2[(wc + 8) * 264 + t];
      o2[wc] = tile2[(wc + 16) * 264 + t];
      o3[wc] = tile2[(wc + 24) * 264 + t];
    }
    size_t xr = ((size_t)b * 4096 + pgrp * 256 + t) * 256 + chunk * 32;
    *(u16x8*)&xpos[xr] = o0;
    *(u16x8*)&xpos[xr + 8] = o1;
    *(u16x8*)&xpos[xr + 16] = o2;
    *(u16x8*)&xpos[xr + 24] = o3;
  }
}

// ---------------- MFMA GEMM: C[M,N] = A[M,256] * B[N,256]^T ----------------
// EPI=2: A = raw sub [NPOS,256]; LN folded into epilogue:
//   out = rstd_m*acc + (-mu_m*rstd_m)*G[o] + Bb[o]   (B = W*gamma, bf16)
// EPI=1: proj GEMM, residual-add epilogue into BCHW.
template<int EPI, int NT>
__global__ __launch_bounds__(256) void k_gemm_mfma(
    const unsigned short* __restrict__ A,
    const unsigned short* __restrict__ Bw,
    unsigned short* __restrict__ Cout,
    const float* __restrict__ bias,
    const unsigned short* __restrict__ subB,
    int ldc,
    const float2* __restrict__ partials,
    const float* __restrict__ Gv,
    const float* __restrict__ Bbv)
{
  __shared__ __align__(16) unsigned short As[128 * 32];
  __shared__ __align__(16) unsigned short Bs[128 * 32];
  __shared__ __align__(16) unsigned short Cs[64 * 136];
  __shared__ float aS[128], bS[128], Gs[128], Bb2[128];
  int flat = blockIdx.x;
  int xcd = flat & 7;
  int l = flat >> 3;
  int ml = l / NT;
  int nn = l - ml * NT;
  int m0 = (xcd * 32 + ml) * 128;
  int n0 = nn * 128;
  int tid = threadIdx.x;
  int wv = tid >> 6;
  int lane = tid & 63;
  int mw = (wv >> 1) * 64, nw = (wv & 1) * 64;
  int r = lane & 15, q = lane >> 4;

  if (EPI == 2) {
    if (tid < 128) {
      int p = m0 + tid;
      float s = 0.f, qq = 0.f;
      #pragma unroll
      for (int ch = 0; ch < 8; ++ch) {
        float2 pp = partials[(size_t)ch * NPOS + p];
        s += pp.x; qq += pp.y;
      }
      float mu = s * (1.f / 256.f);
      float var = qq * (1.f / 256.f) - mu * mu;
      float rs = rsqrtf(var + EPS_);
      aS[tid] = rs;
      bS[tid] = -mu * rs;
      Gs[tid] = Gv[n0 + tid];
      Bb2[tid] = Bbv[n0 + tid];
    }
  }

  int seg0 = wv * 2;
  int srow0 = seg0 * 16 + (lane >> 2);
  int scol = (lane & 3) * 8;
  const unsigned short* ga0 = A  + (size_t)(m0 + srow0) * 256 + scol;
  const unsigned short* ga1 = ga0 + 16 * 256;
  const unsigned short* gb0 = Bw + (size_t)(n0 + srow0) * 256 + scol;
  const unsigned short* gb1 = gb0 + 16 * 256;
  unsigned short* la0 = &As[seg0 * 512];
  unsigned short* la1 = la0 + 512;
  unsigned short* lb0 = &Bs[seg0 * 512];
  unsigned short* lb1 = lb0 + 512;

  f32x4 acc[4][4];
  #pragma unroll
  for (int i = 0; i < 4; ++i)
    #pragma unroll
    for (int j = 0; j < 4; ++j)
      acc[i][j] = (f32x4){0.f, 0.f, 0.f, 0.f};

  for (int k0 = 0; k0 < 256; k0 += 32) {
    GLD_LDS16(ga0 + k0, la0);
    GLD_LDS16(ga1 + k0, la1);
    GLD_LDS16(gb0 + k0, lb0);
    GLD_LDS16(gb1 + k0, lb1);
    __syncthreads();
    bf16x8 af[4], bfr[4];
    #pragma unroll
    for (int mt = 0; mt < 4; ++mt)
      af[mt] = *(const bf16x8*)&As[(mw + mt * 16 + r) * 32 + q * 8];
    #pragma unroll
    for (int nt = 0; nt < 4; ++nt)
      bfr[nt] = *(const bf16x8*)&Bs[(nw + nt * 16 + r) * 32 + q * 8];
    #pragma unroll
    for (int mt = 0; mt < 4; ++mt)
      #pragma unroll
      for (int nt = 0; nt < 4; ++nt)
        acc[mt][nt] = __builtin_amdgcn_mfma_f32_16x16x32_bf16(af[mt], bfr[nt], acc[mt][nt], 0, 0, 0);
    __syncthreads();
  }

  int b = m0 >> 12;
  int nn0 = m0 & 4095;
  #pragma unroll
  for (int pass = 0; pass < 2; ++pass) {
    __syncthreads();
    if (EPI != 1) {
      if ((wv >> 1) == pass) {
        #pragma unroll
        for (int mt = 0; mt < 4; ++mt) {
          int lr = mt * 16 + q * 4;
          #pragma unroll
          for (int nt = 0; nt < 4; ++nt) {
            int col = nw + nt * 16 + r;
            #pragma unroll
            for (int rr = 0; rr < 4; ++rr) {
              float vv = acc[mt][nt][rr];
              if (EPI == 2) {
                int mrow = pass * 64 + lr + rr;
                vv = fmaf(vv, aS[mrow], fmaf(bS[mrow], Gs[col], Bb2[col]));
              }
              Cs[(lr + rr) * 136 + col] = f2bf(vv);
            }
          }
        }
      }
    } else {
      if ((wv & 1) == pass) {
        #pragma unroll
        for (int nt = 0; nt < 4; ++nt) {
          int lr = nt * 16 + r;
          #pragma unroll
          for (int mt = 0; mt < 4; ++mt) {
            int pc = mw + mt * 16 + q * 4;
            #pragma unroll
            for (int rr = 0; rr < 4; ++rr)
              Cs[lr * 136 + pc + rr] = f2bf(acc[mt][nt][rr]);
          }
        }
      }
    }
    __syncthreads();
    if (EPI != 1) {
      #pragma unroll
      for (int cc = 0; cc < 4; ++cc) {
        int ch = cc * 256 + tid;
        int row = ch >> 4, cg = ch & 15;
        u16x8 cv = *(const u16x8*)&Cs[row * 136 + cg * 8];
        int m = m0 + pass * 64 + row;
        *(u16x8*)&Cout[(size_t)m * ldc + n0 + cg * 8] = cv;
      }
    } else {
      #pragma unroll
      for (int cc = 0; cc < 4; ++cc) {
        int ch = cc * 256 + tid;
        int row = ch >> 4, cg = ch & 15;
        u16x8 cv = *(const u16x8*)&Cs[row * 136 + cg * 8];
        int c = n0 + pass * 64 + row;
        size_t idx = ((size_t)(b * 256 + c)) * 4096 + nn0 + cg * 8;
        u16x8 sv = *(const u16x8*)&subB[idx];
        float bb = bias[c];
        u16x8 ov;
        #pragma unroll
        for (int e = 0; e < 8; ++e)
          ov[e] = f2bf(bf2f((unsigned short)cv[e]) + bb + bf2f((unsigned short)sv[e]));
        *(u16x8*)&Cout[idx] = ov;
      }
    }
  }
}

// ---------------- kernel 3: dilated local attention ----------------
__global__ __launch_bounds__(256) void k_attn(
    const unsigned short* __restrict__ qkv,   // [NPOS, 768] bf16
    unsigned short* __restrict__ y)           // [NPOS, 256] bf16
{
  int t = threadIdx.x;
  int sub = t >> 2;
  int lane4 = t & 3;
  int item = blockIdx.x * 64 + sub;
  int ih = item & 7;
  int p = item >> 3;
  int i = ih >> 1, h = ih & 1;
  int dil = i + 1;
  int b = p >> 12;
  int n = p & 4095;
  int py = n >> 6, px = n & 63;
  int off = i * 64 + h * 32 + lane4 * 8;
  const unsigned short* base = qkv + off;

  uint4 qw = *(const uint4*)(base + (size_t)p * 768);
  float q0 = blo(qw.x), q1 = bhi(qw.x), q2 = blo(qw.y), q3 = bhi(qw.y),
        q4 = blo(qw.z), q5 = bhi(qw.z), q6 = blo(qw.w), q7 = bhi(qw.w);

  int pj[9];
  #pragma unroll
  for (int j = 0; j < 9; ++j) {
    int ny = py + (j / 3 - 1) * dil;
    int nx = px + (j % 3 - 1) * dil;
    bool ok = ((unsigned)ny < 64u) && ((unsigned)nx < 64u);
    pj[j] = ok ? ((b << 12) + (ny << 6) + nx) : -1;
  }

  float sc[9];
  #pragma unroll
  for (int j = 0; j < 9; ++j) {
    float s = 0.f;
    if (pj[j] >= 0) {
      uint4 kw = *(const uint4*)(base + 256 + (size_t)pj[j] * 768);
      s  = q0 * blo(kw.x) + q1 * bhi(kw.x);
      s += q2 * blo(kw.y) + q3 * bhi(kw.y);
      s += q4 * blo(kw.z) + q5 * bhi(kw.z);
      s += q6 * blo(kw.w) + q7 * bhi(kw.w);
    }
    s += __shfl_xor(s, 1, 4);
    s += __shfl_xor(s, 2, 4);
    sc[j] = s * SCALE_;             // zero-pad taps -> score exactly 0
  }

  float mx = sc[0];
  #pragma unroll
  for (int j = 1; j < 9; ++j) mx = fmaxf(mx, sc[j]);
  float e[9], ssum = 0.f;
  #pragma unroll
  for (int j = 0; j < 9; ++j) { e[j] = __expf(sc[j] - mx); ssum += e[j]; }
  float inv = 1.f / ssum;

  float o0 = 0.f, o1 = 0.f, o2 = 0.f, o3 = 0.f, o4 = 0.f, o5 = 0.f, o6 = 0.f, o7 = 0.f;
  #pragma unroll
  for (int j = 0; j < 9; ++j) {
    if (pj[j] >= 0) {
      float w = e[j] * inv;
      uint4 vw = *(const uint4*)(base + 512 + (size_t)pj[j] * 768);
      o0 += w * blo(vw.x); o1 += w * bhi(vw.x);
      o2 += w * blo(vw.y); o3 += w * bhi(vw.y);
      o4 += w * blo(vw.z); o5 += w * bhi(vw.z);
      o6 += w * blo(vw.w); o7 += w * bhi(vw.w);
    }
  }

  u16x8 ov;
  ov[0] = f2bf(o0); ov[1] = f2bf(o1); ov[2] = f2bf(o2); ov[3] = f2bf(o3);
  ov[4] = f2bf(o4); ov[5] = f2bf(o5); ov[6] = f2bf(o6); ov[7] = f2bf(o7);
  *(u16x8*)(y + (size_t)p * 256 + off) = ov;
}

// ---------------- kernel 5: per-(b,c) 64x64x64 MFMA matmul, dup output ----
__global__ __launch_bounds__(256) void k_bmm(
    const unsigned short* __restrict__ viB,
    const unsigned short* __restrict__ divmB,
    float* __restrict__ out)
{
  __shared__ __align__(16) unsigned short Vs[64 * 72];
  __shared__ __align__(16) unsigned short Ds[64 * 72];
  int bc = blockIdx.x;
  size_t base = (size_t)bc * 4096;
  int t = threadIdx.x;
  {
    int flat = t * 16;
    int row = flat >> 6, col = flat & 63;   // row: i for vi / k for div
    u16x8 v0 = *(const u16x8*)&viB[base + flat];
    u16x8 v1 = *(const u16x8*)&viB[base + flat + 8];
    *(u16x8*)&Vs[row * 72 + col] = v0;
    *(u16x8*)&Vs[row * 72 + col + 8] = v1;
    u16x8 d0 = *(const u16x8*)&divmB[base + flat];
    u16x8 d1 = *(const u16x8*)&divmB[base + flat + 8];
    #pragma unroll
    for (int e = 0; e < 8; ++e) {
      Ds[(col + e) * 72 + row] = (unsigned short)d0[e];       // Ds[j][k]
      Ds[(col + 8 + e) * 72 + row] = (unsigned short)d1[e];
    }
  }
  __syncthreads();
  int w = t >> 6, lane = t & 63;
  int r = lane & 15, q = lane >> 4;
  int wi = (w >> 1) * 32, wj = (w & 1) * 32;
  f32x4 acc[2][2];
  #pragma unroll
  for (int i = 0; i < 2; ++i)
    #pragma unroll
    for (int j = 0; j < 2; ++j)
      acc[i][j] = (f32x4){0.f, 0.f, 0.f, 0.f};
  #pragma unroll
  for (int ks = 0; ks < 2; ++ks) {
    bf16x8 a[2], bfr[2];
    #pragma unroll
    for (int ti = 0; ti < 2; ++ti)
      a[ti] = *(const bf16x8*)&Vs[(wi + ti * 16 + r) * 72 + ks * 32 + q * 8];
    #pragma unroll
    for (int tj = 0; tj < 2; ++tj)
      bfr[tj] = *(const bf16x8*)&Ds[(wj + tj * 16 + r) * 72 + ks * 32 + q * 8];
    #pragma unroll
    for (int ti = 0; ti < 2; ++ti)
      #pragma unroll
      for (int tj = 0; tj < 2; ++tj)
        acc[ti][tj] = __builtin_amdgcn_mfma_f32_16x16x32_bf16(a[ti], bfr[tj], acc[ti][tj], 0, 0, 0);
  }
  #pragma unroll
  for (int ti = 0; ti < 2; ++ti)
    #pragma unroll
    for (int tj = 0; tj < 2; ++tj)
      #pragma unroll
      for (int rr = 0; rr < 4; ++rr) {
        int row = wi + ti * 16 + q * 4 + rr;
        int col = wj + tj * 16 + r;
        float v = acc[ti][tj][rr];
        out[base + row * 64 + col] = v;
        out[8388608ull + base + row * 64 + col] = v;
      }
}

extern "C" void kernel_launch(void* const* d_in, const int* in_sizes, int n_in,
                              void* d_out, int out_size, void* d_ws, size_t ws_size,
                              hipStream_t stream) {
  const float* vi     = (const float*)d_in[0];
  const float* ir     = (const float*)d_in[1];
  const float* w_qkv  = (const float*)d_in[2];
  const float* proj_w = (const float*)d_in[3];
  const float* proj_b = (const float*)d_in[4];
  const float* ln_g   = (const float*)d_in[5];
  const float* ln_b   = (const float*)d_in[6];
  float* out = (float*)d_out;
  char* ws = (char*)d_ws;
  unsigned short* subB = (unsigned short*)(ws);                // 16.8 MB BCHW bf16
  unsigned short* qkvb = (unsigned short*)(ws + 16777216);     // 50.3 MB [NPOS,768]
  unsigned short* divmB= (unsigned short*)(ws + 16777216);     // reuse after attn
  unsigned short* xpos = (unsigned short*)(ws + 67108864);     // 16.8 MB sub [NPOS,256]
  unsigned short* yb   = (unsigned short*)(ws + 83886080);     // 16.8 MB [NPOS,256]
  unsigned short* viB  = (unsigned short*)(ws + 100663296);    // 16.8 MB BCHW bf16
  unsigned short* wqb  = (unsigned short*)(ws + 117440512);    // [768,256] bf16 (W*gamma)
  unsigned short* pwb  = wqb + 196608;                         // [256,256] bf16
  float2* partials     = (float2*)(ws + 125829120);            // 2 MB [8][NPOS]
  float* Gv            = (float*)(ws + 127926272);             // [768] f32
  float* Bbv           = (float*)(ws + 127930368);             // [768] f32

  k_stream<<<1280, 256, 0, stream>>>(vi, ir, w_qkv, proj_w, ln_g, ln_b,
                                     wqb, subB, viB, xpos, partials, Gv, Bbv);
  k_gemm_mfma<2, 6><<<1536, 256, 0, stream>>>(xpos, wqb, qkvb, nullptr, nullptr, 768,
                                              partials, Gv, Bbv);
  k_attn<<<4096, 256, 0, stream>>>(qkvb, yb);
  k_gemm_mfma<1, 2><<<512, 256, 0, stream>>>(yb, pwb, divmB, proj_b, subB, 0,
                                             nullptr, nullptr, nullptr);
  k_bmm<<<2048, 256, 0, stream>>>(viB, divmB, out);
}